// Round 8
// baseline (492.555 us; speedup 1.0000x reference)
//
#include <hip/hip_runtime.h>

#define BB 4096
#define SS 512
#define NG 256     // 4*HID gate columns
#define BT 16      // batch rows per workgroup (grid = 256 = #CUs)
#define NT 512     // 8 waves: 0-3 compute (MFMA+cell), 4-7 service (head/stage/flush)
#define CH 32      // time-chunk length
#define HSTR 68    // hbuf row stride (shorts)
#define PSTR 16    // pcx row stride (shorts): slots 0..11 real, 12..15 zero
#define SBSTR 264  // sbias row stride (floats), overlaid on pcx
#define OSTR 33    // obuf row stride (floats)

typedef __bf16 bf16_t;
typedef bf16_t bf16x8 __attribute__((ext_vector_type(8)));
typedef bf16_t bf16x4 __attribute__((ext_vector_type(4)));
typedef float  f32x4  __attribute__((ext_vector_type(4)));

__device__ __forceinline__ unsigned short f2bf(float x) {
    union { float f; unsigned u; } q{x};
    unsigned r = (q.u + 0x7fffu + ((q.u >> 16) & 1u)) >> 16;
    return (unsigned short)r;
}
__device__ __forceinline__ float bf2f(unsigned short s) {
    union { unsigned u; float f; } q{((unsigned)s) << 16};
    return q.f;
}
#define LOG2E 1.4426950408889634f
__device__ __forceinline__ float frcp_(float x)  { return __builtin_amdgcn_rcpf(x); }
__device__ __forceinline__ float fexp2_(float x) { return __builtin_amdgcn_exp2f(x); }
__device__ __forceinline__ float flog2_(float x) { return __builtin_amdgcn_logf(x); }
__device__ __forceinline__ float softplus_(float x){ return x > 20.0f ? x : 0.6931471805599453f * flog2_(1.0f + fexp2_(LOG2E * x)); }

// lgkm-only barrier: orders all LDS traffic WITHOUT draining vmcnt — service
// waves' global loads/stores stay in flight across barriers.
__device__ __forceinline__ void bar_lgkm() {
    asm volatile("s_waitcnt lgkmcnt(0)\n\ts_barrier" ::: "memory");
}

// K-slot layout (96): 0..63 = h, 64 = prev, 65..74 = cov, 75 = prev residual, 76..95 = 0.
// Gate columns pre-scaled: i,f,o by -log2e; g by -2log2e:
//   sigma(x) = rcp(1+exp2(y)),  tanh(x) = 2*rcp(1+exp2(z)) - 1.
//
// Swapped-operand GEMM (R7): gates^T = mfma(W_frag, h_frag, C); lane(qd,ln)
// owns units 16wv+qd*4..+3 of batch row ln -> one ds_write_b64 for h.
// This round (issue-shave, R5-calibrated ~1:1 issue->step sensitivity):
//  - pcx step address flattened to (t+1)&63 (layout is contiguous over the
//    2-buffer x 32-step dimension), obuf flattened to (t-1)&63.
//  - hbuf read/write bases precomputed as pointer pairs, parity-selected.
//  - `if (t+1 < SS)` guards dropped: at t=511 the prefetch reads valid stale
//    LDS and the extra acc_pre is dead — both harmless, saves cmp+branch/step.
// Waves 0-3 compute; wave 4 head; waves 4-7 staging/flush (commit t%32==8,
// flush t%32==16). One lgkm-only barrier per step.
__global__ __launch_bounds__(NT)
void deepar_kernel(const float* __restrict__ target, const float* __restrict__ cov,
                   const int* __restrict__ cats, const float* __restrict__ scale,
                   const float* __restrict__ emb0, const float* __restrict__ emb1,
                   const float* __restrict__ emb2, const float* __restrict__ emb3,
                   const float* __restrict__ w_ih, const float* __restrict__ w_hh,
                   const float* __restrict__ bias, const float* __restrict__ w_out,
                   const float* __restrict__ b_out, float* __restrict__ out)
{
    // pcx (2*32*16*16 shorts = 32768 B) overlays sbias(16896 B)+sx(4352 B) scratch
    __shared__ __attribute__((aligned(16))) unsigned char smemA[2 * CH * BT * PSTR * 2];
    __shared__ __attribute__((aligned(16))) unsigned short hbuf[2][BT][HSTR]; //  4352 B
    __shared__ float obuf[2 * CH][OSTR];                                      //  8448 B
    __shared__ float inv_s[BT], scl_s[BT];

    unsigned short* pcx   = (unsigned short*)smemA;
    float*          sbias = (float*)smemA;
    float*          sx    = (float*)(smemA + BT * SBSTR * 4);

    const int tid  = threadIdx.x;
    const int b0   = blockIdx.x * BT;
    const int lane = tid & 63;
    const int wv   = tid >> 6;
    const int qd   = lane >> 4;
    const int ln   = lane & 15;
    const bool is_compute = (wv < 4);
    const int tid2 = tid & 255;          // index within service half (wv>=4)

    // ---------------- setup ----------------
    for (int i = tid; i < 2 * BT * HSTR; i += NT) ((unsigned short*)hbuf)[i] = 0;
    if (tid < BT) {
        float s = scale[b0 + tid];
        scl_s[tid] = s;
        inv_s[tid] = 1.0f / fmaxf(s, 1e-4f);
        sx[tid * 68 + 64] = log1pf(s);
    }
    if (tid < BT * 4) {
        int r = tid >> 2, e = tid & 3;
        int c = cats[(b0 + r) * 4 + e];
        const float* eb = (e == 0 ? emb0 : e == 1 ? emb1 : e == 2 ? emb2 : emb3);
        for (int j = 0; j < 16; ++j) sx[r * 68 + e * 16 + j] = eb[c * 16 + j];
    }
    __syncthreads();

    // sbias[r][n] = bias[n] + static_x[r] . w_ih[11..75][n]; n = tid&255, rows split by tid>>8
    {
        const int n = tid & 255, half = tid >> 8;
        float bj = bias[n];
        float acc[8];
        #pragma unroll
        for (int r = 0; r < 8; ++r) acc[r] = bj;
        for (int k = 0; k < 65; ++k) {
            float w = w_ih[(11 + k) * NG + n];
            #pragma unroll
            for (int r = 0; r < 8; ++r) acc[r] += sx[(half * 8 + r) * 68 + k] * w;
        }
        #pragma unroll
        for (int r = 0; r < 8; ++r) sbias[(half * 8 + r) * SBSTR + n] = acc[r];
    }
    __syncthreads();

    // ---------------- register-resident weights + sbias fragments (compute waves) ----------------
    bf16x8 bfrag[4][3];
    f32x4  sbf[4];
    if (is_compute) {
        #pragma unroll
        for (int ti = 0; ti < 4; ++ti) {
            const float gsc = (ti == 2) ? (-2.0f * LOG2E) : (-LOG2E);
            const int n = ln + 16 * (wv + 4 * ti);   // gate ti, unit 16wv+ln (weight col)
            #pragma unroll
            for (int c = 0; c < 3; ++c) {
                #pragma unroll
                for (int j = 0; j < 8; ++j) {
                    int k = qd * 8 + 32 * c + j;
                    float w;
                    if (k < 64)                  w = w_hh[k * NG + n];
                    else if (k == 64 || k == 75) w = w_ih[n];
                    else if (k <= 74)            w = w_ih[(k - 64) * NG + n];
                    else                         w = 0.0f;
                    bfrag[ti][c][j] = (bf16_t)(w * gsc);
                }
            }
            // swapped C layout: lane(qd,ln) holds D[unit 16wv+qd*4+r][batch ln]
            #pragma unroll
            for (int r = 0; r < 4; ++r)
                sbf[ti][r] = sbias[ln * SBSTR + (16 * (wv + 4 * ti) + qd * 4 + r)] * gsc;
        }
    }

    // head fragments: w_out^T as A operand, C = b_out rows
    bf16x8 wob0, wob1;
    f32x4  bC;
    #pragma unroll
    for (int j = 0; j < 8; ++j) {
        wob0[j] = (bf16_t)((ln < 2) ? w_out[(qd * 8 + j) * 2 + ln] : 0.0f);
        wob1[j] = (bf16_t)((ln < 2) ? w_out[(32 + qd * 8 + j) * 2 + ln] : 0.0f);
    }
    #pragma unroll
    for (int r = 0; r < 4; ++r)
        bC[r] = (qd == 0 && r < 2) ? b_out[r] : 0.0f;
    const float sclh = scl_s[ln];   // batch-row scale for head lane (qd==0 path)

    __syncthreads();   // all sbias/sx reads done -> safe to overwrite with pcx

    // zero pcx (both buffers; establishes the permanent-zero slots 12..15)
    for (int i = tid; i < (2 * CH * BT * PSTR) / 2; i += NT) ((int*)smemA)[i] = 0;
    __syncthreads();

    // fill pcx chunk 0 (steps 0..31)
    if (tid < 256) {
        const int row = tid >> 4, i5 = tid & 15;
        const float* cr = cov + (size_t)(b0 + row) * (SS * 10);
        #pragma unroll
        for (int j = 0; j < 20; ++j) {
            int e = i5 + 16 * j, tp = e / 10, k = e - 10 * tp;
            pcx[((0 * CH + tp) * BT + row) * PSTR + 1 + k] = f2bf(cr[e]);
        }
        float pv0 = (i5 == 0) ? 0.0f : target[(size_t)(b0 + row) * SS + i5 - 1] * inv_s[row];
        float pv1 = target[(size_t)(b0 + row) * SS + i5 + 15] * inv_s[row];
        unsigned short m0 = f2bf(pv0), m1 = f2bf(pv1);
        pcx[((0 * CH + i5) * BT + row) * PSTR + 0]       = m0;
        pcx[((0 * CH + i5) * BT + row) * PSTR + 11]      = f2bf(pv0 - bf2f(m0));
        pcx[((0 * CH + i5 + 16) * BT + row) * PSTR + 0]  = m1;
        pcx[((0 * CH + i5 + 16) * BT + row) * PSTR + 11] = f2bf(pv1 - bf2f(m1));
    }
    __syncthreads();

    // hoisted hbuf pointers: read base per parity, write base per parity
    const unsigned short* hbA = &hbuf[0][ln][0];            // read when t even
    const unsigned short* hbB = &hbuf[1][ln][0];            // read when t odd
    unsigned short* hwA = &hbuf[0][ln][16 * wv + qd * 4];   // write when t odd  (nxt=0)
    unsigned short* hwB = &hbuf[1][ln][16 * wv + qd * 4];   // write when t even (nxt=1)
    // pcx a2 base (lane-fixed part): step s reads pcx[((s&63)*BT + ln)*PSTR + qd*8]
    const unsigned short* a2base = &pcx[(size_t)ln * PSTR + qd * 8];

    // prime a2(0) and acc_pre(0) = x-part of gates^T for t=0 (compute waves)
    bf16x8 a2 = {};
    f32x4 acc_pre[4];
    if (is_compute) {
        if (qd < 2)
            a2 = *(const bf16x8*)a2base;   // step 0 -> (0&63)=0
        #pragma unroll
        for (int ti = 0; ti < 4; ++ti)
            acc_pre[ti] = __builtin_amdgcn_mfma_f32_16x16x32_bf16(bfrag[ti][2], a2, sbf[ti], 0, 0, 0);
    }

    float cst[4] = {0.0f, 0.0f, 0.0f, 0.0f};   // c-state: units 16wv+qd*4+r, batch row ln
    float crg[20];
    #pragma unroll
    for (int j = 0; j < 20; ++j) crg[j] = 0.0f;
    float trg0 = 0.0f, trg1 = 0.0f;

    // ---------------- time loop (ONE lgkm-only barrier per step) ----------------
    for (int t = 0; t < SS; ++t) {
        bar_lgkm();        // hbuf[t&1] complete; acc_pre already holds x-part of gates(t)

        if (is_compute) {
            // ---- recurrence waves: 2-deep swapped MFMA chain + lane-local cell ----
            const unsigned short* hb = (t & 1) ? hbB : hbA;
            bf16x8 a0 = *(const bf16x8*)(hb + qd * 8);
            bf16x8 a1 = *(const bf16x8*)(hb + 32 + qd * 8);

            f32x4 acc0 = __builtin_amdgcn_mfma_f32_16x16x32_bf16(bfrag[0][0], a0, acc_pre[0], 0, 0, 0);
            f32x4 acc1 = __builtin_amdgcn_mfma_f32_16x16x32_bf16(bfrag[1][0], a0, acc_pre[1], 0, 0, 0);
            f32x4 acc2 = __builtin_amdgcn_mfma_f32_16x16x32_bf16(bfrag[2][0], a0, acc_pre[2], 0, 0, 0);
            f32x4 acc3 = __builtin_amdgcn_mfma_f32_16x16x32_bf16(bfrag[3][0], a0, acc_pre[3], 0, 0, 0);
            acc0 = __builtin_amdgcn_mfma_f32_16x16x32_bf16(bfrag[0][1], a1, acc0, 0, 0, 0);
            acc1 = __builtin_amdgcn_mfma_f32_16x16x32_bf16(bfrag[1][1], a1, acc1, 0, 0, 0);
            acc2 = __builtin_amdgcn_mfma_f32_16x16x32_bf16(bfrag[2][1], a1, acc2, 0, 0, 0);
            acc3 = __builtin_amdgcn_mfma_f32_16x16x32_bf16(bfrag[3][1], a1, acc3, 0, 0, 0);

            // prefetch a2 for t+1 (pcx stable; committed >=23 steps earlier).
            // No t-guard: at t=511 this reads valid stale LDS, result unused.
            if (qd < 2)
                a2 = *(const bf16x8*)(a2base + ((t + 1) & 63) * (BT * PSTR));

            // lane-local LSTM cell: units 16wv+qd*4+r, batch row ln
            // acc0/1/3 = -log2e * (i,f,o preact); acc2 = -2log2e * g preact
            bf16x4 hq;
            #pragma unroll
            for (int r = 0; r < 4; ++r) {
                float si = frcp_(1.0f + fexp2_(acc0[r]));
                float sf = frcp_(1.0f + fexp2_(acc1[r]));
                float tg = 2.0f * frcp_(1.0f + fexp2_(acc2[r])) - 1.0f;
                float so = frcp_(1.0f + fexp2_(acc3[r]));
                float cc = sf * cst[r] + si * tg;
                cst[r] = cc;
                float th = 2.0f * frcp_(1.0f + fexp2_((-2.0f * LOG2E) * cc)) - 1.0f;
                hq[r] = (bf16_t)(so * th);
            }
            // 4 consecutive units of row ln -> ONE ds_write_b64
            *(bf16x4*)((t & 1) ? hwA : hwB) = hq;

            // x-part of gates for t+1 (no guard: dead at t=511, executes under barrier wait)
            #pragma unroll
            for (int ti = 0; ti < 4; ++ti)
                acc_pre[ti] = __builtin_amdgcn_mfma_f32_16x16x32_bf16(bfrag[ti][2], a2, sbf[ti], 0, 0, 0);
        } else {
            // ---- service waves ----
            if ((t & 31) == 0 && t < 480) {
                const int row = tid2 >> 4, i5 = tid2 & 15, t0n = t + CH;
                const float* cr = cov + (size_t)(b0 + row) * (SS * 10) + t0n * 10;
                #pragma unroll
                for (int j = 0; j < 20; ++j) crg[j] = cr[i5 + 16 * j];
                const float* tr = target + (size_t)(b0 + row) * SS + t0n + i5;
                trg0 = tr[-1];
                trg1 = tr[15];
            }

            // head for t-1 via swapped MFMA on wave 4: D[outcol][batch]
            if (wv == 4 && t > 0) {
                const unsigned short* hb = (t & 1) ? hbB : hbA;
                bf16x8 a0 = *(const bf16x8*)(hb + qd * 8);
                bf16x8 a1 = *(const bf16x8*)(hb + 32 + qd * 8);
                f32x4 hacc = __builtin_amdgcn_mfma_f32_16x16x32_bf16(wob0, a0, bC, 0, 0, 0);
                hacc = __builtin_amdgcn_mfma_f32_16x16x32_bf16(wob1, a1, hacc, 0, 0, 0);
                if (qd == 0) {
                    float sp0 = softplus_(hacc[0]) + 1e-4f;   // mu_s
                    float sp1 = softplus_(hacc[1]) + 1e-4f;   // alpha
                    obuf[(t - 1) & 63][ln]      = sp0 * sclh;
                    obuf[(t - 1) & 63][16 + ln] = sp1;
                }
            }

            if ((t & 31) == 8) {
                const int c = t >> 5;
                if (c < 15) {   // commit chunk c+1 (loads issued at t%32==0, 8 steps ago)
                    const int row = tid2 >> 4, i5 = tid2 & 15, nb = (c + 1) & 1;
                    float pv0 = trg0 * inv_s[row];
                    float pv1 = trg1 * inv_s[row];
                    unsigned short m0 = f2bf(pv0), m1 = f2bf(pv1);
                    pcx[((nb * CH + i5) * BT + row) * PSTR + 0]       = m0;
                    pcx[((nb * CH + i5) * BT + row) * PSTR + 11]      = f2bf(pv0 - bf2f(m0));
                    pcx[((nb * CH + i5 + 16) * BT + row) * PSTR + 0]  = m1;
                    pcx[((nb * CH + i5 + 16) * BT + row) * PSTR + 11] = f2bf(pv1 - bf2f(m1));
                    #pragma unroll
                    for (int j = 0; j < 20; ++j) {
                        int e = i5 + 16 * j, tp = e / 10, k = e - 10 * tp;
                        pcx[((nb * CH + tp) * BT + row) * PSTR + 1 + k] = f2bf(crg[j]);
                    }
                }
            }

            if ((t & 31) == 16) {
                const int c = t >> 5;
                if (c >= 1) {   // flush obuf chunk c-1
                    const int pb = (c - 1) & 1, t0p = (c - 1) << 5;
                    #pragma unroll
                    for (int h = 0; h < 4; ++h) {
                        int e = tid2 + 256 * h;
                        int tte = e & 31, rowe = (e >> 5) & 15, pe = e >> 9;
                        out[(pe ? (BB * SS) : 0) + (size_t)(b0 + rowe) * SS + t0p + tte] =
                            obuf[pb * CH + tte][pe * 16 + rowe];
                    }
                }
            }
        }
    }

    // ---------------- epilogue: head for t=511 (h in hbuf[0]) + flush chunk 15 ----------------
    __syncthreads();
    if (wv == 4) {
        const unsigned short* hb = hbA;
        bf16x8 a0 = *(const bf16x8*)(hb + qd * 8);
        bf16x8 a1 = *(const bf16x8*)(hb + 32 + qd * 8);
        f32x4 hacc = __builtin_amdgcn_mfma_f32_16x16x32_bf16(wob0, a0, bC, 0, 0, 0);
        hacc = __builtin_amdgcn_mfma_f32_16x16x32_bf16(wob1, a1, hacc, 0, 0, 0);
        if (qd == 0) {
            float sp0 = softplus_(hacc[0]) + 1e-4f;
            float sp1 = softplus_(hacc[1]) + 1e-4f;
            obuf[63][ln]      = sp0 * sclh;
            obuf[63][16 + ln] = sp1;
        }
    }
    __syncthreads();
    #pragma unroll
    for (int h = 0; h < 2; ++h) {
        int e = tid + NT * h;
        int tte = e & 31, rowe = (e >> 5) & 15, pe = e >> 9;
        out[(pe ? (BB * SS) : 0) + (size_t)(b0 + rowe) * SS + 480 + tte] =
            obuf[CH + tte][pe * 16 + rowe];
    }
}

extern "C" void kernel_launch(void* const* d_in, const int* in_sizes, int n_in,
                              void* d_out, int out_size, void* d_ws, size_t ws_size,
                              hipStream_t stream) {
    deepar_kernel<<<BB / BT, NT, 0, stream>>>(
        (const float*)d_in[0], (const float*)d_in[1], (const int*)d_in[2],
        (const float*)d_in[3], (const float*)d_in[4], (const float*)d_in[5],
        (const float*)d_in[6], (const float*)d_in[7], (const float*)d_in[8],
        (const float*)d_in[9], (const float*)d_in[10], (const float*)d_in[11],
        (const float*)d_in[12], (float*)d_out);
}